// Round 2
// baseline (483.233 us; speedup 1.0000x reference)
//
#include <hip/hip_runtime.h>
#include <hip/hip_bf16.h>
#include <stdint.h>

#define B_SZ 4096
#define F_SZ 3072
#define NCLS 1000
#define NE 8
#define NPAD 1024
#define CAP 4096

// workspace layout (bytes)
#define OFF_CNT   0          // 8 ints
#define OFF_LIST  1024       // 8*4096 ints = 131072
#define OFF_PAIR  132096     // 4096 ints
#define OFF_XB    262144     // 4096*3072 bf16 = 25165824
#define OFF_WT    25427968   // 8*1024*3072 bf16 = 50331648  (end ~75.8MB)

typedef unsigned short u16;
typedef __attribute__((ext_vector_type(8))) short short8v;  // 8 bf16 (4 VGPRs)
typedef __attribute__((ext_vector_type(4))) float f32x4;

__device__ __forceinline__ u16 f2bf(float f) {
  unsigned int u = __float_as_uint(f);
  u = (u + 0x7FFFu + ((u >> 16) & 1u)) >> 16;  // RNE, inputs are finite
  return (u16)u;
}

__device__ __forceinline__ void gll16(const void* g, void* l) {
  __builtin_amdgcn_global_load_lds(
      (const __attribute__((address_space(1))) void*)g,
      (__attribute__((address_space(3))) void*)l, 16, 0, 0);
}

// ---------------- ens_w f32 [e][k][n] -> bf16 wt [e][n][k] ----------------
__global__ __launch_bounds__(256) void transpose_w(const float* __restrict__ ensw,
                                                   u16* __restrict__ wt) {
  __shared__ u16 tile[64 * 68];  // [k][n], pad 68 to soften column-read conflicts
  int t = threadIdx.x;
  int n0 = blockIdx.x * 64, k0 = blockIdx.y * 64, e = blockIdx.z;
  const float* src = ensw + (size_t)e * (F_SZ * NCLS);
  int kr = t >> 4, nq = (t & 15) * 4;
  for (int it = 0; it < 4; ++it) {
    int kk = kr + it * 16;
    const float* sp = src + (size_t)(k0 + kk) * NCLS + n0 + nq;
    float4 v;
    if (n0 + nq + 3 < NCLS) v = *(const float4*)sp;
    else {
      v.x = (n0 + nq     < NCLS) ? sp[0] : 0.f;
      v.y = (n0 + nq + 1 < NCLS) ? sp[1] : 0.f;
      v.z = (n0 + nq + 2 < NCLS) ? sp[2] : 0.f;
      v.w = (n0 + nq + 3 < NCLS) ? sp[3] : 0.f;
    }
    u16* d = tile + kk * 68 + nq;
    d[0] = f2bf(v.x); d[1] = f2bf(v.y); d[2] = f2bf(v.z); d[3] = f2bf(v.w);
  }
  __syncthreads();
  int rn = t >> 3, c8 = t & 7;
  for (int it = 0; it < 2; ++it) {
    int n = rn + it * 32;
    u16 o[8];
#pragma unroll
    for (int jj = 0; jj < 8; ++jj) o[jj] = tile[(c8 * 8 + jj) * 68 + n];
    uint4 pk;
    pk.x = (unsigned)o[0] | ((unsigned)o[1] << 16);
    pk.y = (unsigned)o[2] | ((unsigned)o[3] << 16);
    pk.z = (unsigned)o[4] | ((unsigned)o[5] << 16);
    pk.w = (unsigned)o[6] | ((unsigned)o[7] << 16);
    *(uint4*)(wt + ((size_t)(e * NPAD + n0 + n)) * F_SZ + k0 + c8 * 8) = pk;
  }
}

// ---------------- selector CNN + routing + x->bf16 ----------------
// 1 wave = 1 sample; block = 2 waves.
// x staged in LDS with ROW STRIDE 36 floats (36 % 32 = 4 -> bank quads rotate
// per row; stride 32 made all 28 y-lanes hit the same banks: ~28-way conflict).
#define XST 36
#define XCH 1152  // 32*36
__global__ __launch_bounds__(128) void selector(
    const float* __restrict__ x,
    const float* __restrict__ w1, const float* __restrict__ b1,
    const float* __restrict__ w2, const float* __restrict__ b2,
    const float* __restrict__ w3, const float* __restrict__ b3,
    const float* __restrict__ fw, const float* __restrict__ fb,
    u16* __restrict__ xb16, int* __restrict__ cnt, int* __restrict__ list,
    int* __restrict__ expair) {
  __shared__ float wgt[384];
  __shared__ float S[2][4704];
  int t = threadIdx.x;
  for (int i = t; i < 372; i += 128) {
    float v;
    if      (i <  75) v = w1[i];
    else if (i <  76) v = b1[i - 75];
    else if (i < 126) v = w2[i - 76];
    else if (i < 128) v = b2[i - 126];
    else if (i < 328) v = w3[i - 128];
    else if (i < 332) v = b3[i - 328];
    else if (i < 364) v = fw[i - 332];
    else              v = fb[i - 364];
    wgt[i] = v;
  }
  int w = t >> 6, l = t & 63;
  int b = blockIdx.x * 2 + w;
  float* xs   = S[w];
  float* buf1 = xs + 3456;  // 28x28
  float* p1   = xs + 4240;  // 14x14
  float* buf2 = xs + 4436;  // 2x10x10
  float* p2   = xs + 4636;  // 2x5x5
  float* hb   = xs + 4686;  // 4
  float* zb   = xs + 4690;  // 8

  // stage x (f32, padded rows) + emit bf16 copy
  const float4* gx = (const float4*)(x + (size_t)b * F_SZ);
  ushort4* gxb = (ushort4*)(xb16 + (size_t)b * F_SZ);
  for (int it = 0; it < 12; ++it) {
    int idx = it * 64 + l;
    float4 v = gx[idx];
    int f = idx * 4;
    int c = f >> 10, rem = f & 1023, y = rem >> 5, xc = rem & 31;
    *(float4*)(xs + c * XCH + y * XST + xc) = v;
    ushort4 h4;
    h4.x = f2bf(v.x); h4.y = f2bf(v.y); h4.z = f2bf(v.z); h4.w = f2bf(v.w);
    gxb[idx] = h4;
  }
  __syncthreads();

  // conv1 3->1 ch, 5x5, out 28x28. lane -> (row y, half xh); 14 outputs/lane.
  if (l < 56) {
    int y = l >> 1, xh = l & 1;
    float acc[14];
#pragma unroll
    for (int xc = 0; xc < 14; ++xc) acc[xc] = wgt[75];
    for (int c = 0; c < 3; ++c)
      for (int i = 0; i < 5; ++i) {
        const float4* rb = (const float4*)(xs + c * XCH + (y + i) * XST) + xh * 3;
        float a[20];
#pragma unroll
        for (int q = 0; q < 5; ++q) {
          float4 v = rb[q];
          a[q * 4] = v.x; a[q * 4 + 1] = v.y; a[q * 4 + 2] = v.z; a[q * 4 + 3] = v.w;
        }
        if (xh) {  // shift window by 2 (xh*14 - 12)
#pragma unroll
          for (int q = 0; q < 18; ++q) a[q] = a[q + 2];
        }
        const float* wp = wgt + c * 25 + i * 5;
        float W0 = wp[0], W1 = wp[1], W2 = wp[2], W3 = wp[3], W4 = wp[4];
#pragma unroll
        for (int xc = 0; xc < 14; ++xc)
          acc[xc] += a[xc] * W0 + a[xc + 1] * W1 + a[xc + 2] * W2 + a[xc + 3] * W3 + a[xc + 4] * W4;
      }
#pragma unroll
    for (int xc = 0; xc < 14; ++xc) buf1[y * 28 + xh * 14 + xc] = fmaxf(acc[xc], 0.f);
  }
  __syncthreads();

  // pool1 -> 14x14
  for (int it = 0; it < 4; ++it) {
    int p = it * 64 + l;
    if (p < 196) {
      int py = p / 14, px = p % 14;
      const float* r0 = buf1 + (2 * py) * 28 + 2 * px;
      p1[p] = fmaxf(fmaxf(r0[0], r0[1]), fmaxf(r0[28], r0[29]));
    }
  }
  __syncthreads();

  // conv2 1->2 ch, out 2x10x10
  for (int it = 0; it < 4; ++it) {
    int p = it * 64 + l;
    if (p < 200) {
      int o = p / 100, rem = p % 100, yy = rem / 10, xx = rem % 10;
      float acc = wgt[126 + o];
      const float* wp = wgt + 76 + o * 25;
      for (int i = 0; i < 5; ++i)
#pragma unroll
        for (int j = 0; j < 5; ++j) acc += p1[(yy + i) * 14 + xx + j] * wp[i * 5 + j];
      buf2[p] = fmaxf(acc, 0.f);
    }
  }
  __syncthreads();

  // pool2 -> 2x5x5
  if (l < 50) {
    int o = l / 25, rem = l % 25, yy = rem / 5, xx = rem % 5;
    const float* r0 = buf2 + o * 100 + (2 * yy) * 10 + 2 * xx;
    p2[l] = fmaxf(fmaxf(r0[0], r0[1]), fmaxf(r0[10], r0[11]));
  }
  __syncthreads();

  // conv3 2->4 ch, 5x5 over 5x5 -> 4 scalars
  if (l < 4) {
    float acc = wgt[328 + l];
    const float* wp = wgt + 128 + l * 50;
    for (int cc = 0; cc < 50; ++cc) acc += p2[cc] * wp[cc];
    hb[l] = fmaxf(acc, 0.f);
  }
  __syncthreads();

  // fc -> z[8]
  if (l < 8) {
    float acc = wgt[364 + l];
    const float* wp = wgt + 332 + l * 4;
#pragma unroll
    for (int j = 0; j < 4; ++j) acc += hb[j] * wp[j];
    zb[l] = acc;
  }
  __syncthreads();

  // top-2 (normalization is a positive scale: order-preserving -> skip)
  if (l == 0) {
    float zz[8];
#pragma unroll
    for (int e = 0; e < 8; ++e) zz[e] = zb[e];
    int e1 = 0; float v1 = zz[0];
    for (int e = 1; e < 8; ++e) if (zz[e] > v1) { v1 = zz[e]; e1 = e; }
    int e2 = -1; float v2 = 0.f;
    for (int e = 0; e < 8; ++e) {
      if (e == e1) continue;
      if (e2 < 0 || zz[e] > v2) { v2 = zz[e]; e2 = e; }
    }
    int p1i = atomicAdd(&cnt[e1], 1); list[e1 * CAP + p1i] = b;
    int p2i = atomicAdd(&cnt[e2], 1); list[e2 * CAP + p2i] = b;
    expair[b] = e1 | (e2 << 8);
  }
}

// ---------------- out[b] = ens_b[e1] + ens_b[e2] ----------------
__global__ __launch_bounds__(256) void bias_init(const int* __restrict__ expair,
                                                 const float* __restrict__ ensb,
                                                 float* __restrict__ out) {
  int b = blockIdx.x;
  int t = threadIdx.x;
  if (t >= 250) return;
  int pr = expair[b];
  const float4* p1 = (const float4*)(ensb + (size_t)(pr & 255) * NCLS);
  const float4* p2 = (const float4*)(ensb + (size_t)((pr >> 8) & 255) * NCLS);
  float4* op = (float4*)(out + (size_t)b * NCLS);
  float4 a = p1[t], c = p2[t];
  float4 r; r.x = a.x + c.x; r.y = a.y + c.y; r.z = a.z + c.z; r.w = a.w + c.w;
  op[t] = r;
}

// ---------------- grouped gather-GEMM, 128x128x64 bf16 MFMA ----------------
// Double-buffered: prefetch K-tile t+1 via global_load_lds while computing t.
// One __syncthreads per step (drains vmcnt for the prefetch + protects reuse).
__global__ __launch_bounds__(256) void moe_gemm(const u16* __restrict__ xb,
                                                const u16* __restrict__ wt,
                                                const int* __restrict__ cnt,
                                                const int* __restrict__ list,
                                                float* __restrict__ out) {
  __shared__ u16 As[2][8192];   // [buf][128 rows][64 k] bf16, 16B-chunk swizzled
  __shared__ u16 Bs[2][8192];
  __shared__ int idx_s[128];
  int e = blockIdx.z;
  int cnt_e = cnt[e];
  int m0 = blockIdx.y * 128;
  if (m0 >= cnt_e) return;
  int n0 = blockIdx.x * 128;
  int t = threadIdx.x;
  const int* lst = list + e * CAP;
  if (t < 128) idx_s[t] = lst[min(m0 + t, cnt_e - 1)];  // clamp pad rows
  __syncthreads();

  // staging: per operand 1024 16B-chunks; chunk c: row=c>>3, lds slot=c&7.
  // Effective layout swizzle slot' = slot ^ (row&7) realized by PRE-SWIZZLING
  // the global source (gll dest must stay linear): src chunk g = (c&7)^(row&7).
  int tr = t >> 3;                 // row within 32-row group
  int ts = t & 7;                  // lds slot
  int g  = ts ^ (tr & 7);          // source chunk (const per thread: 32%8==0)
  const u16* pA[4]; const u16* pB[4]; int ldst[4];
#pragma unroll
  for (int q = 0; q < 4; ++q) {
    int row = q * 32 + tr;
    pA[q] = xb + (size_t)idx_s[row] * F_SZ + g * 8;
    pB[q] = wt + ((size_t)(e * NPAD + n0 + row)) * F_SZ + g * 8;
    ldst[q] = (q * 256 + t) * 8;   // linear 16B-chunk dest (u16 index)
  }

  int w = t >> 6, l = t & 63;
  int lr = l & 15, hk = l >> 4;
  int wrow = (w >> 1) * 64, wcol = (w & 1) * 64;
  int rA[4], rB[4];
#pragma unroll
  for (int i = 0; i < 4; ++i) {
    rA[i] = (wrow + i * 16 + lr) * 64;
    rB[i] = (wcol + i * 16 + lr) * 64;
  }
  int sw0 = ((hk    ) ^ (lr & 7)) * 8;   // k-chunk hk,   swizzled
  int sw1 = ((hk + 4) ^ (lr & 7)) * 8;   // k-chunk hk+4, swizzled

  // prologue: stage step 0 into buf 0
#pragma unroll
  for (int q = 0; q < 4; ++q) { gll16(pA[q], &As[0][ldst[q]]); pA[q] += 64; }
#pragma unroll
  for (int q = 0; q < 4; ++q) { gll16(pB[q], &Bs[0][ldst[q]]); pB[q] += 64; }
  __syncthreads();

  f32x4 acc[4][4] = {};
  for (int s = 0; s < 48; ++s) {
    int cur = s & 1;
    if (s < 47) {
      int nxt = cur ^ 1;
#pragma unroll
      for (int q = 0; q < 4; ++q) { gll16(pA[q], &As[nxt][ldst[q]]); pA[q] += 64; }
#pragma unroll
      for (int q = 0; q < 4; ++q) { gll16(pB[q], &Bs[nxt][ldst[q]]); pB[q] += 64; }
    }
    short8v av[2][4], bv[2][4];
#pragma unroll
    for (int i = 0; i < 4; ++i) {
      av[0][i] = *(const short8v*)(&As[cur][rA[i] + sw0]);
      av[1][i] = *(const short8v*)(&As[cur][rA[i] + sw1]);
      bv[0][i] = *(const short8v*)(&Bs[cur][rB[i] + sw0]);
      bv[1][i] = *(const short8v*)(&Bs[cur][rB[i] + sw1]);
    }
#pragma unroll
    for (int h = 0; h < 2; ++h)
#pragma unroll
      for (int i = 0; i < 4; ++i)
#pragma unroll
        for (int j = 0; j < 4; ++j)
          acc[i][j] = __builtin_amdgcn_mfma_f32_16x16x32_bf16(av[h][i], bv[h][j], acc[i][j], 0, 0, 0);
    __syncthreads();
  }

  // epilogue: scatter-add (each sample hit by exactly 2 experts)
#pragma unroll
  for (int i = 0; i < 4; ++i) {
#pragma unroll
    for (int r = 0; r < 4; ++r) {
      int mt = wrow + i * 16 + hk * 4 + r;
      if (m0 + mt < cnt_e) {
        float* orow = out + (size_t)idx_s[mt] * NCLS;
#pragma unroll
        for (int j = 0; j < 4; ++j) {
          int col = n0 + wcol + j * 16 + lr;
          if (col < NCLS) unsafeAtomicAdd(orow + col, acc[i][j][r]);
        }
      }
    }
  }
}

extern "C" void kernel_launch(void* const* d_in, const int* in_sizes, int n_in,
                              void* d_out, int out_size, void* d_ws, size_t ws_size,
                              hipStream_t stream) {
  const float* x   = (const float*)d_in[0];
  const float* w1  = (const float*)d_in[1];
  const float* b1  = (const float*)d_in[2];
  const float* w2  = (const float*)d_in[3];
  const float* b2  = (const float*)d_in[4];
  const float* w3  = (const float*)d_in[5];
  const float* b3  = (const float*)d_in[6];
  const float* fw  = (const float*)d_in[7];
  const float* fb  = (const float*)d_in[8];
  const float* ensw = (const float*)d_in[9];
  const float* ensb = (const float*)d_in[10];
  float* out = (float*)d_out;

  uint8_t* ws = (uint8_t*)d_ws;
  int* cnt    = (int*)(ws + OFF_CNT);
  int* list   = (int*)(ws + OFF_LIST);
  int* expair = (int*)(ws + OFF_PAIR);
  u16* xb16   = (u16*)(ws + OFF_XB);
  u16* wt     = (u16*)(ws + OFF_WT);

  hipMemsetAsync(cnt, 0, 64, stream);
  transpose_w<<<dim3(16, 48, 8), 256, 0, stream>>>(ensw, wt);
  selector<<<2048, 128, 0, stream>>>(x, w1, b1, w2, b2, w3, b3, fw, fb,
                                     xb16, cnt, list, expair);
  bias_init<<<4096, 256, 0, stream>>>(expair, ensb, out);
  moe_gemm<<<dim3(8, 32, 8), 256, 0, stream>>>(xb16, wt, cnt, list, out);
}

// Round 3
// 439.591 us; speedup vs baseline: 1.0993x; 1.0993x over previous
//
#include <hip/hip_runtime.h>
#include <hip/hip_bf16.h>
#include <stdint.h>

#define B_SZ 4096
#define F_SZ 3072
#define NCLS 1000
#define NE 8
#define NPAD 1024
#define CAP 4096
#define KSPLIT 2
#define KCH (F_SZ / KSPLIT)   // 1536

// workspace layout (bytes)
#define OFF_CNT   0          // 8 ints
#define OFF_LIST  1024       // 8*4096 ints = 131072
#define OFF_PAIR  132096     // 4096 ints
#define OFF_XB    262144     // 4096*3072 bf16 = 25165824
#define OFF_WT    25427968   // 8*1024*3072 bf16 = 50331648  (end ~75.8MB)

typedef unsigned short u16;
typedef __attribute__((ext_vector_type(8))) short short8v;  // 8 bf16 (4 VGPRs)
typedef __attribute__((ext_vector_type(4))) float f32x4;

__device__ __forceinline__ u16 f2bf(float f) {
  unsigned int u = __float_as_uint(f);
  u = (u + 0x7FFFu + ((u >> 16) & 1u)) >> 16;  // RNE, inputs are finite
  return (u16)u;
}

__device__ __forceinline__ void gll16(const void* g, void* l) {
  __builtin_amdgcn_global_load_lds(
      (const __attribute__((address_space(1))) void*)g,
      (__attribute__((address_space(3))) void*)l, 16, 0, 0);
}

// ---------------- ens_w f32 [e][k][n] -> bf16 wt [e][n][k] ----------------
// 256k x 64n tile per block, staged [n][k] in LDS so global writes are
// 512B-contiguous per 32-lane group (was 128B segments).
__global__ __launch_bounds__(256) void transpose_w(const float* __restrict__ ensw,
                                                   u16* __restrict__ wt) {
  __shared__ u16 tile[64 * 264];   // [n][k], k-stride 264 (528B = 33*16, b128-aligned)
  int t = threadIdx.x;
  int n0 = blockIdx.x * 64, k0 = blockIdx.y * 256, e = blockIdx.z;
  const float* src = ensw + (size_t)e * (F_SZ * NCLS);
  int kr = t >> 4, nq = (t & 15) * 4;
  for (int it = 0; it < 16; ++it) {
    int kk = it * 16 + kr;
    const float* sp = src + (size_t)(k0 + kk) * NCLS + n0 + nq;
    int n = n0 + nq;
    float4 v = make_float4(0.f, 0.f, 0.f, 0.f);
    if (n + 3 < NCLS) v = *(const float4*)sp;
    else {
      if (n     < NCLS) v.x = sp[0];
      if (n + 1 < NCLS) v.y = sp[1];
      if (n + 2 < NCLS) v.z = sp[2];
      if (n + 3 < NCLS) v.w = sp[3];
    }
    u16* d = tile + nq * 264 + kk;
    d[0]   = f2bf(v.x);
    d[264] = f2bf(v.y);
    d[528] = f2bf(v.z);
    d[792] = f2bf(v.w);
  }
  __syncthreads();
  int kc = t & 31, nr = t >> 5;
  for (int it = 0; it < 8; ++it) {
    int n = it * 8 + nr;
    uint4 pk = *(const uint4*)(tile + n * 264 + kc * 8);
    *(uint4*)(wt + ((size_t)(e * NPAD + n0 + n)) * F_SZ + k0 + kc * 8) = pk;
  }
}

// ---------------- selector CNN + routing + x->bf16 ----------------
// 1 wave = 1 sample; block = 2 waves. x row stride 36 (bank rotation).
#define XST 36
#define XCH 1152  // 32*36
__global__ __launch_bounds__(128) void selector(
    const float* __restrict__ x,
    const float* __restrict__ w1, const float* __restrict__ b1,
    const float* __restrict__ w2, const float* __restrict__ b2,
    const float* __restrict__ w3, const float* __restrict__ b3,
    const float* __restrict__ fw, const float* __restrict__ fb,
    u16* __restrict__ xb16, int* __restrict__ cnt, int* __restrict__ list,
    int* __restrict__ expair) {
  __shared__ float wgt[384];
  __shared__ float S[2][4704];
  int t = threadIdx.x;
  for (int i = t; i < 372; i += 128) {
    float v;
    if      (i <  75) v = w1[i];
    else if (i <  76) v = b1[i - 75];
    else if (i < 126) v = w2[i - 76];
    else if (i < 128) v = b2[i - 126];
    else if (i < 328) v = w3[i - 128];
    else if (i < 332) v = b3[i - 328];
    else if (i < 364) v = fw[i - 332];
    else              v = fb[i - 364];
    wgt[i] = v;
  }
  int w = t >> 6, l = t & 63;
  int b = blockIdx.x * 2 + w;
  float* xs   = S[w];
  float* buf1 = xs + 3456;  // 28x28
  float* p1   = xs + 4240;  // 14x14
  float* buf2 = xs + 4436;  // 2x10x10
  float* p2   = xs + 4636;  // 2x5x5
  float* hb   = xs + 4686;  // 4
  float* zb   = xs + 4690;  // 8

  const float4* gx = (const float4*)(x + (size_t)b * F_SZ);
  ushort4* gxb = (ushort4*)(xb16 + (size_t)b * F_SZ);
  for (int it = 0; it < 12; ++it) {
    int idx = it * 64 + l;
    float4 v = gx[idx];
    int f = idx * 4;
    int c = f >> 10, rem = f & 1023, y = rem >> 5, xc = rem & 31;
    *(float4*)(xs + c * XCH + y * XST + xc) = v;
    ushort4 h4;
    h4.x = f2bf(v.x); h4.y = f2bf(v.y); h4.z = f2bf(v.z); h4.w = f2bf(v.w);
    gxb[idx] = h4;
  }
  __syncthreads();

  // conv1 3->1 ch, 5x5, out 28x28; lane -> (row y, half xh); 14 outputs/lane
  if (l < 56) {
    int y = l >> 1, xh = l & 1;
    float acc[14];
#pragma unroll
    for (int xc = 0; xc < 14; ++xc) acc[xc] = wgt[75];
    for (int c = 0; c < 3; ++c)
      for (int i = 0; i < 5; ++i) {
        const float4* rb = (const float4*)(xs + c * XCH + (y + i) * XST) + xh * 3;
        float a[20];
#pragma unroll
        for (int q = 0; q < 5; ++q) {
          float4 v = rb[q];
          a[q * 4] = v.x; a[q * 4 + 1] = v.y; a[q * 4 + 2] = v.z; a[q * 4 + 3] = v.w;
        }
        if (xh) {
#pragma unroll
          for (int q = 0; q < 18; ++q) a[q] = a[q + 2];
        }
        const float* wp = wgt + c * 25 + i * 5;
        float W0 = wp[0], W1 = wp[1], W2 = wp[2], W3 = wp[3], W4 = wp[4];
#pragma unroll
        for (int xc = 0; xc < 14; ++xc)
          acc[xc] += a[xc] * W0 + a[xc + 1] * W1 + a[xc + 2] * W2 + a[xc + 3] * W3 + a[xc + 4] * W4;
      }
#pragma unroll
    for (int xc = 0; xc < 14; ++xc) buf1[y * 28 + xh * 14 + xc] = fmaxf(acc[xc], 0.f);
  }
  __syncthreads();

  // pool1 -> 14x14
  for (int it = 0; it < 4; ++it) {
    int p = it * 64 + l;
    if (p < 196) {
      int py = p / 14, px = p % 14;
      const float* r0 = buf1 + (2 * py) * 28 + 2 * px;
      p1[p] = fmaxf(fmaxf(r0[0], r0[1]), fmaxf(r0[28], r0[29]));
    }
  }
  __syncthreads();

  // conv2 1->2 ch, out 2x10x10 (fully unrolled 5x5 -> 25 independent reads)
  for (int it = 0; it < 4; ++it) {
    int p = it * 64 + l;
    if (p < 200) {
      int o = p / 100, rem = p % 100, yy = rem / 10, xx = rem % 10;
      float acc = wgt[126 + o];
      const float* wp = wgt + 76 + o * 25;
#pragma unroll
      for (int i = 0; i < 5; ++i)
#pragma unroll
        for (int j = 0; j < 5; ++j) acc += p1[(yy + i) * 14 + xx + j] * wp[i * 5 + j];
      buf2[p] = fmaxf(acc, 0.f);
    }
  }
  __syncthreads();

  // pool2 -> 2x5x5
  if (l < 50) {
    int o = l / 25, rem = l % 25, yy = rem / 5, xx = rem % 5;
    const float* r0 = buf2 + o * 100 + (2 * yy) * 10 + 2 * xx;
    p2[l] = fmaxf(fmaxf(r0[0], r0[1]), fmaxf(r0[10], r0[11]));
  }
  __syncthreads();

  // conv3 2->4 ch (fully unrolled: 50 independent ds_reads, not a latency chain)
  if (l < 4) {
    float acc = wgt[328 + l];
    const float* wp = wgt + 128 + l * 50;
#pragma unroll
    for (int cc = 0; cc < 50; ++cc) acc += p2[cc] * wp[cc];
    hb[l] = fmaxf(acc, 0.f);
  }
  __syncthreads();

  // fc -> z[8]
  if (l < 8) {
    float acc = wgt[364 + l];
    const float* wp = wgt + 332 + l * 4;
#pragma unroll
    for (int j = 0; j < 4; ++j) acc += hb[j] * wp[j];
    zb[l] = acc;
  }
  __syncthreads();

  // top-2 (L2-norm is a positive scale: order-preserving -> skip)
  if (l == 0) {
    float zz[8];
#pragma unroll
    for (int e = 0; e < 8; ++e) zz[e] = zb[e];
    int e1 = 0; float v1 = zz[0];
    for (int e = 1; e < 8; ++e) if (zz[e] > v1) { v1 = zz[e]; e1 = e; }
    int e2 = -1; float v2 = 0.f;
    for (int e = 0; e < 8; ++e) {
      if (e == e1) continue;
      if (e2 < 0 || zz[e] > v2) { v2 = zz[e]; e2 = e; }
    }
    int p1i = atomicAdd(&cnt[e1], 1); list[e1 * CAP + p1i] = b;
    int p2i = atomicAdd(&cnt[e2], 1); list[e2 * CAP + p2i] = b;
    expair[b] = e1 | (e2 << 8);
  }
}

// ---------------- out[b] = ens_b[e1] + ens_b[e2] ----------------
__global__ __launch_bounds__(256) void bias_init(const int* __restrict__ expair,
                                                 const float* __restrict__ ensb,
                                                 float* __restrict__ out) {
  int b = blockIdx.x;
  int t = threadIdx.x;
  if (t >= 250) return;
  int pr = expair[b];
  const float4* p1 = (const float4*)(ensb + (size_t)(pr & 255) * NCLS);
  const float4* p2 = (const float4*)(ensb + (size_t)((pr >> 8) & 255) * NCLS);
  float4* op = (float4*)(out + (size_t)b * NCLS);
  float4 a = p1[t], c = p2[t];
  float4 r; r.x = a.x + c.x; r.y = a.y + c.y; r.z = a.z + c.z; r.w = a.w + c.w;
  op[t] = r;
}

// ---------------- grouped gather-GEMM, 128x128 tile, BK=64, K-split x2 ----
// Single-buffered LDS (33KB -> 4-5 blocks/CU resident); latency hidden by
// cross-block wave overlap (m114), not intra-block prefetch (m97 lesson).
__global__ __launch_bounds__(256, 4) void moe_gemm(const u16* __restrict__ xb,
                                                   const u16* __restrict__ wt,
                                                   const int* __restrict__ cnt,
                                                   const int* __restrict__ list,
                                                   float* __restrict__ out) {
  __shared__ u16 As[8192];   // [128 rows][64 k], 16B-chunk swizzled
  __shared__ u16 Bs[8192];
  __shared__ int idx_s[128];
  int e = blockIdx.z >> 1, ks = blockIdx.z & 1;
  int cnt_e = cnt[e];
  int m0 = blockIdx.y * 128;
  if (m0 >= cnt_e) return;
  int n0 = blockIdx.x * 128;
  int t = threadIdx.x;
  const int* lst = list + e * CAP;
  if (t < 128) idx_s[t] = lst[min(m0 + t, cnt_e - 1)];  // clamp pad rows
  __syncthreads();

  // staging: per operand 1024 16B-chunks; chunk c: row=c>>3, lds slot=c&7.
  // Swizzle slot' = slot ^ (row&7) realized by pre-swizzling the global source
  // (gll dest must stay linear): src chunk g = (t&7) ^ (row&7).
  int tr = t >> 3, ts = t & 7;
  int g  = ts ^ (tr & 7);
  const u16* pA[4]; const u16* pB[4]; int ldst[4];
#pragma unroll
  for (int q = 0; q < 4; ++q) {
    int row = q * 32 + tr;
    pA[q] = xb + (size_t)idx_s[row] * F_SZ + ks * KCH + g * 8;
    pB[q] = wt + ((size_t)(e * NPAD + n0 + row)) * F_SZ + ks * KCH + g * 8;
    ldst[q] = (q * 256 + t) * 8;
  }

  int w = t >> 6, l = t & 63;
  int lr = l & 15, hk = l >> 4;
  int wrow = (w >> 1) * 64, wcol = (w & 1) * 64;
  int rA[4], rB[4];
#pragma unroll
  for (int i = 0; i < 4; ++i) {
    rA[i] = (wrow + i * 16 + lr) * 64;
    rB[i] = (wcol + i * 16 + lr) * 64;
  }
  int sw0 = ((hk    ) ^ (lr & 7)) * 8;
  int sw1 = ((hk + 4) ^ (lr & 7)) * 8;

  // prologue: stage step 0
#pragma unroll
  for (int q = 0; q < 4; ++q) { gll16(pA[q], &As[ldst[q]]); pA[q] += 64; }
#pragma unroll
  for (int q = 0; q < 4; ++q) { gll16(pB[q], &Bs[ldst[q]]); pB[q] += 64; }

  f32x4 acc[4][4] = {};
  for (int s = 0; s < KCH / 64; ++s) {
    __syncthreads();  // drains vmcnt for the stage just issued
    short8v av[2][4], bv[2][4];
#pragma unroll
    for (int i = 0; i < 4; ++i) {
      av[0][i] = *(const short8v*)(&As[rA[i] + sw0]);
      av[1][i] = *(const short8v*)(&As[rA[i] + sw1]);
      bv[0][i] = *(const short8v*)(&Bs[rB[i] + sw0]);
      bv[1][i] = *(const short8v*)(&Bs[rB[i] + sw1]);
    }
#pragma unroll
    for (int h = 0; h < 2; ++h)
#pragma unroll
      for (int i = 0; i < 4; ++i)
#pragma unroll
        for (int j = 0; j < 4; ++j)
          acc[i][j] = __builtin_amdgcn_mfma_f32_16x16x32_bf16(av[h][i], bv[h][j], acc[i][j], 0, 0, 0);
    if (s < KCH / 64 - 1) {
      __syncthreads();  // protect LDS before restaging
#pragma unroll
      for (int q = 0; q < 4; ++q) { gll16(pA[q], &As[ldst[q]]); pA[q] += 64; }
#pragma unroll
      for (int q = 0; q < 4; ++q) { gll16(pB[q], &Bs[ldst[q]]); pB[q] += 64; }
    }
  }

  // epilogue: scatter-add (each sample hit by exactly 2 experts x KSPLIT blocks)
#pragma unroll
  for (int i = 0; i < 4; ++i) {
#pragma unroll
    for (int r = 0; r < 4; ++r) {
      int mt = wrow + i * 16 + hk * 4 + r;
      if (m0 + mt < cnt_e) {
        float* orow = out + (size_t)idx_s[mt] * NCLS;
#pragma unroll
        for (int j = 0; j < 4; ++j) {
          int col = n0 + wcol + j * 16 + lr;
          if (col < NCLS) unsafeAtomicAdd(orow + col, acc[i][j][r]);
        }
      }
    }
  }
}

extern "C" void kernel_launch(void* const* d_in, const int* in_sizes, int n_in,
                              void* d_out, int out_size, void* d_ws, size_t ws_size,
                              hipStream_t stream) {
  const float* x   = (const float*)d_in[0];
  const float* w1  = (const float*)d_in[1];
  const float* b1  = (const float*)d_in[2];
  const float* w2  = (const float*)d_in[3];
  const float* b2  = (const float*)d_in[4];
  const float* w3  = (const float*)d_in[5];
  const float* b3  = (const float*)d_in[6];
  const float* fw  = (const float*)d_in[7];
  const float* fb  = (const float*)d_in[8];
  const float* ensw = (const float*)d_in[9];
  const float* ensb = (const float*)d_in[10];
  float* out = (float*)d_out;

  uint8_t* ws = (uint8_t*)d_ws;
  int* cnt    = (int*)(ws + OFF_CNT);
  int* list   = (int*)(ws + OFF_LIST);
  int* expair = (int*)(ws + OFF_PAIR);
  u16* xb16   = (u16*)(ws + OFF_XB);
  u16* wt     = (u16*)(ws + OFF_WT);

  hipMemsetAsync(cnt, 0, 64, stream);
  transpose_w<<<dim3(16, 12, 8), 256, 0, stream>>>(ensw, wt);
  selector<<<2048, 128, 0, stream>>>(x, w1, b1, w2, b2, w3, b3, fw, fb,
                                     xb16, cnt, list, expair);
  bias_init<<<4096, 256, 0, stream>>>(expair, ensb, out);
  moe_gemm<<<dim3(8, 32, 16), 256, 0, stream>>>(xb16, wt, cnt, list, out);
}